// Round 7
// baseline (118.104 us; speedup 1.0000x reference)
//
#include <hip/hip_runtime.h>
#include <math.h>

// EnhancedFinancialGAT — analytical collapse (Round 0 proof: all N=2000 node
// rows identical + per-dst softmax sums to 1 (self-loop guarantees denom>=1)
// => each GAT layer is a dense 256->256 relu; edges/attention irrelevant).
//
// Round 7: fp16 activations + packed fdot2. R6 analysis: kernel is bound by
// LDS-read issue (16 ds_read_b128/lane/layer for fp32 acts ~= 7.4 us) and
// VALU MAC issue. Storing activations as fp16 halves the LDS instruction
// count; __builtin_amdgcn_fdot2 (f16x2 dot + f32 acc) halves MAC instrs.
// Register weight-frag pipelining (R6), LDS bias staging, fp16 weight
// prepass all retained. Expected absmax ~1e-3 (threshold 1e-2).

#define B_ITEMS 64

typedef _Float16 half_t;
typedef _Float16 half2_t __attribute__((ext_vector_type(2)));
typedef _Float16 half8 __attribute__((ext_vector_type(8)));

// ---- fp16 weight layout inside d_ws (element offsets, all mult. of 8) ----
#define OFF_WIN   0        // W_in   [256x64]   16384
#define OFF_GAT   16384    // gat_W  [3x256x256] 196608
#define OFF_FUSE  212992   // W_fuse [256x320]  81920
#define OFF_P1    294912   // W_p1   [128x256]  32768
#define OFF_D1    327680   // W_d1   [128x256]  32768
#define OFF_P2    360448   // W_p2   [64x128]   8192
#define OFF_D2    368640   // W_d2   [64x128]   8192
#define TOT_W     376832   // total halves (753664 B)

// ---- bias layout in LDS (float offsets) ----
#define BIN   0
#define BGAT  256
#define BFUSE 1024
#define BP1   1280
#define BD1   1408
#define BP2   1536
#define BD2   1600
#define NBIAS 1664

// Prepass: fp32 -> fp16, 8 elements/thread. 46 x 1024 threads = TOT_W/8.
extern "C" __global__ __launch_bounds__(1024) void compress_w(
    const float* __restrict__ W_in, const float* __restrict__ gat_W,
    const float* __restrict__ W_fuse, const float* __restrict__ W_p1,
    const float* __restrict__ W_d1, const float* __restrict__ W_p2,
    const float* __restrict__ W_d2, half_t* __restrict__ ws)
{
    const int e = (blockIdx.x * 1024 + threadIdx.x) * 8;
    const float* src;
    int off;
    if      (e < OFF_GAT)  { src = W_in;   off = e; }
    else if (e < OFF_FUSE) { src = gat_W;  off = e - OFF_GAT; }
    else if (e < OFF_P1)   { src = W_fuse; off = e - OFF_FUSE; }
    else if (e < OFF_D1)   { src = W_p1;   off = e - OFF_P1; }
    else if (e < OFF_P2)   { src = W_d1;   off = e - OFF_D1; }
    else if (e < OFF_D2)   { src = W_p2;   off = e - OFF_P2; }
    else                   { src = W_d2;   off = e - OFF_D2; }
    const float4* s4 = reinterpret_cast<const float4*>(src + off);
    float4 a = s4[0], b = s4[1];
    half8 h = { (_Float16)a.x, (_Float16)a.y, (_Float16)a.z, (_Float16)a.w,
                (_Float16)b.x, (_Float16)b.y, (_Float16)b.z, (_Float16)b.w };
    *reinterpret_cast<half8*>(ws + e) = h;
}

// Weight fragment for one layer: this lane's K-slice of its output row.
template <int K, int G>
struct WFrag { half8 w[K / (8 * G)]; };

template <int K, int G>
__device__ __forceinline__ void load_frag(WFrag<K, G>& f,
                                          const half_t* __restrict__ Wh, int t) {
    const int c = t & (G - 1);
    const int o = t / G;
    const half8* __restrict__ W8 =
        reinterpret_cast<const half8*>(Wh + (size_t)o * K);
#pragma unroll
    for (int j = 0; j < K / (8 * G); ++j) f.w[j] = W8[j * G + c];
}

// out[M](fp16) = relu(frag @ in(fp16) + b), frag in registers. t in [0, M*G).
template <int M, int K, int G>
__device__ __forceinline__ void compute_frag(const WFrag<K, G>& f,
                                             const float* __restrict__ bias,   // LDS fp32
                                             const half_t* __restrict__ in,    // LDS fp16
                                             half_t* __restrict__ out,         // LDS fp16
                                             int t) {
    const int c = t & (G - 1);
    const int o = t / G;
    const half8* __restrict__ A8 = reinterpret_cast<const half8*>(in);
    float acc = 0.f;
#pragma unroll
    for (int j = 0; j < K / (8 * G); ++j) {
        const int idx = j * G + c;
        half8 a = A8[idx];
        half8 w = f.w[j];
        half2_t a0 = { a[0], a[1] }, a1 = { a[2], a[3] };
        half2_t a2 = { a[4], a[5] }, a3 = { a[6], a[7] };
        half2_t w0 = { w[0], w[1] }, w1 = { w[2], w[3] };
        half2_t w2 = { w[4], w[5] }, w3 = { w[6], w[7] };
        acc = __builtin_amdgcn_fdot2(a0, w0, acc, false);
        acc = __builtin_amdgcn_fdot2(a1, w1, acc, false);
        acc = __builtin_amdgcn_fdot2(a2, w2, acc, false);
        acc = __builtin_amdgcn_fdot2(a3, w3, acc, false);
    }
#pragma unroll
    for (int s = 1; s < G; s <<= 1) acc += __shfl_xor(acc, s, 64);
    if (c == 0) out[o] = (half_t)fmaxf(acc + bias[o], 0.f);
}

extern "C" __global__ __launch_bounds__(1024) void fin_gat_v7(
    const float* __restrict__ x,        // [64,64]
    const int* __restrict__ cidx,       // [64]
    const half_t* __restrict__ ws,      // fp16 weights (layout above)
    const float* __restrict__ b_in,
    const float* __restrict__ gat_b,    // [3,256]
    const float* __restrict__ emb,      // [2000,64]
    const float* __restrict__ b_fuse,
    const float* __restrict__ b_p1,
    const float* __restrict__ b_p2,
    const float* __restrict__ W_p3, const float* __restrict__ b_p3,
    const float* __restrict__ b_d1,
    const float* __restrict__ b_d2,
    const float* __restrict__ W_d3, const float* __restrict__ b_d3,
    float* __restrict__ out)            // [128]
{
    __shared__ __align__(16) half_t bufA[320];
    __shared__ __align__(16) half_t bufB[320];
    __shared__ float bias_lds[NBIAS];

    const int b = blockIdx.x;
    const int t = threadIdx.x;

    // ---- initial burst: L0 weights, x/emb, all biases, head dot weights ----
    WFrag<64, 4> f_in;
    load_frag(f_in, ws + OFF_WIN, t);

    if (t < 64) {
        const int ci = cidx[b];
        bufA[t] = (half_t)x[b * 64 + t];
        bufA[256 + t] = (half_t)emb[(size_t)ci * 64 + t];   // kept for fuse
    }
    float wdot = 0.f, bdot = 0.f;
    if (t < 64)            wdot = W_p3[t];
    else if (t < 128)      wdot = W_d3[t - 64];
    if (t == 0)            bdot = b_p3[0];
    else if (t == 64)      bdot = b_d3[0];

#pragma unroll
    for (int i = t; i < NBIAS; i += 1024) {
        float v;
        if      (i < 256)  v = b_in[i];
        else if (i < 1024) v = gat_b[i - 256];
        else if (i < 1280) v = b_fuse[i - 1024];
        else if (i < 1408) v = b_p1[i - 1280];
        else if (i < 1536) v = b_d1[i - 1408];
        else if (i < 1600) v = b_p2[i - 1536];
        else               v = b_d2[i - 1600];
        bias_lds[i] = v;
    }
    __syncthreads();

    // ---- L0: h = relu(W_in x): A[0:64] -> B[0:256] ----
    WFrag<256, 4> fg0;
    load_frag(fg0, ws + OFF_GAT + 0 * 65536, t);            // prefetch L1
    compute_frag<256, 64, 4>(f_in, bias_lds + BIN, bufA, bufB, t);
    __syncthreads();

    // ---- L1 (GAT1): B -> A[0:256]  (emb intact in A[256:320]) ----
    WFrag<256, 4> fg1;
    load_frag(fg1, ws + OFF_GAT + 1 * 65536, t);            // prefetch L2
    compute_frag<256, 256, 4>(fg0, bias_lds + BGAT, bufB, bufA, t);
    __syncthreads();

    // ---- L2 (GAT2): A -> B ----
    WFrag<256, 4> fg2;
    load_frag(fg2, ws + OFF_GAT + 2 * 65536, t);            // prefetch L3
    compute_frag<256, 256, 4>(fg1, bias_lds + BGAT + 256, bufA, bufB, t);
    __syncthreads();

    // ---- L3 (GAT3): B -> A[0:256] ----
    WFrag<320, 4> f_fu;
    load_frag(f_fu, ws + OFF_FUSE, t);                      // prefetch fuse
    compute_frag<256, 256, 4>(fg2, bias_lds + BGAT + 512, bufB, bufA, t);
    __syncthreads();

    // ---- L4 (fuse): A[0:320] -> B[0:256] ----
    WFrag<256, 4> f_h1;
    load_frag(f_h1, (t < 512) ? ws + OFF_P1 : ws + OFF_D1, t & 511);  // heads-1
    compute_frag<256, 320, 4>(f_fu, bias_lds + BFUSE, bufA, bufB, t);
    __syncthreads();

    // ---- L5: p1 (lower half-block) / d1 (upper half-block) ----
    WFrag<128, 8> f_h2;
    load_frag(f_h2, (t < 512) ? ws + OFF_P2 : ws + OFF_D2, t & 511);  // heads-2
    if (t < 512) compute_frag<128, 256, 4>(f_h1, bias_lds + BP1, bufB, bufA, t);
    else         compute_frag<128, 256, 4>(f_h1, bias_lds + BD1, bufB, bufA + 192, t - 512);
    __syncthreads();

    // ---- L6: p2 / d2 ----
    if (t < 512) compute_frag<64, 128, 8>(f_h2, bias_lds + BP2, bufA, bufB, t);
    else         compute_frag<64, 128, 8>(f_h2, bias_lds + BD2, bufA + 192, bufB + 64, t - 512);
    __syncthreads();

    // ---- final dots (weights preloaded): wave 0 -> price, wave 1 -> dir ----
    if (t < 64) {
        float v = wdot * (float)bufB[t];
#pragma unroll
        for (int off = 32; off > 0; off >>= 1) v += __shfl_down(v, off, 64);
        if (t == 0) out[b] = v + bdot;
    } else if (t < 128) {
        const int u = t - 64;
        float v = wdot * (float)bufB[64 + u];
#pragma unroll
        for (int off = 32; off > 0; off >>= 1) v += __shfl_down(v, off, 64);
        if (u == 0) {
            float z = v + bdot;
            out[B_ITEMS + b] = 1.0f / (1.0f + expf(-z));
        }
    }
}

extern "C" void kernel_launch(void* const* d_in, const int* in_sizes, int n_in,
                              void* d_out, int out_size, void* d_ws, size_t ws_size,
                              hipStream_t stream) {
    const float* x      = (const float*)d_in[0];
    const int*   cidx   = (const int*)  d_in[1];
    // d_in[2]=edge_index, d_in[3]=edge_attr -> numerically irrelevant
    const float* W_in   = (const float*)d_in[4];
    const float* b_in   = (const float*)d_in[5];
    const float* gat_W  = (const float*)d_in[6];
    // d_in[7..10] = att params -> irrelevant
    const float* gat_b  = (const float*)d_in[11];
    const float* emb    = (const float*)d_in[12];
    const float* W_fuse = (const float*)d_in[13];
    const float* b_fuse = (const float*)d_in[14];
    const float* W_p1   = (const float*)d_in[15];
    const float* b_p1   = (const float*)d_in[16];
    const float* W_p2   = (const float*)d_in[17];
    const float* b_p2   = (const float*)d_in[18];
    const float* W_p3   = (const float*)d_in[19];
    const float* b_p3   = (const float*)d_in[20];
    const float* W_d1   = (const float*)d_in[21];
    const float* b_d1   = (const float*)d_in[22];
    const float* W_d2   = (const float*)d_in[23];
    const float* b_d2   = (const float*)d_in[24];
    const float* W_d3   = (const float*)d_in[25];
    const float* b_d3   = (const float*)d_in[26];

    half_t* ws = (half_t*)d_ws;   // needs 753664 B of scratch

    compress_w<<<46, 1024, 0, stream>>>(W_in, gat_W, W_fuse, W_p1, W_d1,
                                        W_p2, W_d2, ws);

    fin_gat_v7<<<B_ITEMS, 1024, 0, stream>>>(
        x, cidx, ws, b_in, gat_b, emb, b_fuse,
        b_p1, b_p2, W_p3, b_p3, b_d1, b_d2, W_d3, b_d3,
        (float*)d_out);
}